// Round 2
// baseline (9626.051 us; speedup 1.0000x reference)
//
#include <hip/hip_runtime.h>
#include <math.h>

// SPDNet: out = log(W X W^T) via Chebyshev matrix polynomial (ReEig is a no-op
// since spec(X) >= 0.1). All GEMMs are bf16 MFMA with hi/lo split (bf16x3).
// All matrices involved are symmetric -> every GEMM is NT with row-slab staging.

typedef unsigned short u16;
typedef __attribute__((ext_vector_type(8))) short bf16x8;
typedef __attribute__((ext_vector_type(4))) float f32x4;

#define SLOT_U16 131072   // u16 per 256KB slot
#define SLOT_F32 65536
#define LO_OFF   65536    // u16 offset of lo plane within a pair slot

__device__ __forceinline__ u16 f2bf(float x) {
    union { float f; unsigned u; } v; v.f = x;
    return (u16)((v.u + 0x7fffu + ((v.u >> 16) & 1u)) >> 16);
}
__device__ __forceinline__ float bf2f(u16 h) {
    union { float f; unsigned u; } v; v.u = ((unsigned)h) << 16; return v.f;
}

// paired-row swizzled LDS layout: plane = 64 lines x 128B; logical (row,kch)
__device__ __forceinline__ int lds_byte(int row, int kch) {
    int line = row >> 1;
    int slot = (((row & 1) << 2) | kch) ^ (line & 7);
    return line * 128 + slot * 16;
}
__device__ __forceinline__ void lds_decode(int o, int& row, int& kch) {
    int line = o >> 7;
    int slot = ((o >> 4) & 7) ^ (line & 7);
    row = (line << 1) | (slot >> 2);
    kch = slot & 3;
}

// stage one operand's 128x32 K-tile into (ph, pl) LDS planes (u16[4096] each)
template<bool SPLITSRC>
__device__ __forceinline__ void stage_op(
    const u16* srcH, const u16* srcL, const float* srcF,
    int ldK, int rowbase, int kk, u16* ph, u16* pl, int tid)
{
#pragma unroll
    for (int s = 0; s < 2; ++s) {
        int o = s * 4096 + tid * 16;
        int row, kch; lds_decode(o, row, kch);
        size_t ge = (size_t)(rowbase + row) * ldK + kk + kch * 8;
        if constexpr (SPLITSRC) {
            bf16x8 h = *(const bf16x8*)(srcH + ge);
            bf16x8 l = *(const bf16x8*)(srcL + ge);
            *(bf16x8*)((char*)ph + o) = h;
            *(bf16x8*)((char*)pl + o) = l;
        } else {
            float4 f0 = *(const float4*)(srcF + ge);
            float4 f1 = *(const float4*)(srcF + ge + 4);
            float fv[8] = {f0.x,f0.y,f0.z,f0.w,f1.x,f1.y,f1.z,f1.w};
            bf16x8 h, l;
#pragma unroll
            for (int j = 0; j < 8; ++j) {
                u16 hb = f2bf(fv[j]);
                u16 lb = f2bf(fv[j] - bf2f(hb));
                h[j] = (short)hb; l[j] = (short)lb;
            }
            *(bf16x8*)((char*)ph + o) = h;
            *(bf16x8*)((char*)pl + o) = l;
        }
    }
}

// MODE 0 (G1): T1 = W[f] * X[b]      (256x512, K=512), split-store to T1H/T1L planes
// MODE 1 (G2): Mt = (T1 * W[f]^T)*scale - dsub*I   (256x256, K=512)
// MODE 2 (CH): Bnew = alpha*Mt*B1 - B2 + ck*I (in-place over B2), 256x256, K=256
template<int MODE>
__global__ __launch_bounds__(256) void k_gemm(
    const float* Wf, const float* Xf,
    const u16* AH, const u16* AL, const u16* BH,
    u16* OH, u16* OL,
    int p0, float alpha, float ck, float scale, float dsub)
{
    constexpr int KTOT = (MODE == 2) ? 256 : 512;
    constexpr int LDK  = (MODE == 2) ? 256 : 512;
    constexpr int LDO  = (MODE == 0) ? 512 : 256;

    __shared__ u16 sAh[4096], sAl[4096], sBh[4096], sBl[4096];

    const int tid = threadIdx.x;
    const int blk = blockIdx.x;
    int g, tm, tn;
    if constexpr (MODE == 0) { g = blk >> 3; tm = (blk >> 2) & 1; tn = blk & 3; }
    else                     { g = blk >> 2; tm = (blk >> 1) & 1; tn = blk & 1; }
    const int p = p0 + g, bidx = p >> 3, f = p & 7;

    const float *Af32 = nullptr, *Bf32 = nullptr;
    const u16 *AsH = nullptr, *AsL = nullptr, *BsH = nullptr, *BsL = nullptr;
    if constexpr (MODE == 0) {
        Af32 = Wf + (size_t)f * 131072;     // W[f]: 256x512
        Bf32 = Xf + (size_t)bidx * 262144;  // X[b]: 512x512 (symmetric -> rows as cols)
    } else if constexpr (MODE == 1) {
        AsH = AH + (size_t)g * SLOT_U16; AsL = AL + (size_t)g * SLOT_U16;
        Bf32 = Wf + (size_t)f * 131072;     // W rows = output cols (NT)
    } else {
        AsH = AH + (size_t)g * SLOT_U16; AsL = AsH + LO_OFF;
        BsH = BH + (size_t)g * SLOT_U16; BsL = BsH + LO_OFF;
    }
    u16* outH = OH + (size_t)g * SLOT_U16;
    u16* outL;
    if constexpr (MODE == 0) outL = OL + (size_t)g * SLOT_U16;
    else                     outL = outH + LO_OFF;

    const int lane = tid & 63, wid = tid >> 6;
    const int wr = wid >> 1, wc = wid & 1;
    const int frow = lane & 15, fk = lane >> 4;

    int aoff[4], boff[4];
#pragma unroll
    for (int m = 0; m < 4; ++m) aoff[m] = lds_byte(wr*64 + m*16 + frow, fk);
#pragma unroll
    for (int n = 0; n < 4; ++n) boff[n] = lds_byte(wc*64 + n*16 + frow, fk);

    f32x4 acc[4][4];
#pragma unroll
    for (int m = 0; m < 4; ++m)
#pragma unroll
        for (int n = 0; n < 4; ++n) acc[m][n] = (f32x4){0.f,0.f,0.f,0.f};

    for (int kk = 0; kk < KTOT; kk += 32) {
        __syncthreads();
        if constexpr (MODE == 0) {
            stage_op<false>(nullptr,nullptr,Af32, LDK, tm*128, kk, sAh, sAl, tid);
            stage_op<false>(nullptr,nullptr,Bf32, LDK, tn*128, kk, sBh, sBl, tid);
        } else if constexpr (MODE == 1) {
            stage_op<true >(AsH, AsL, nullptr, LDK, tm*128, kk, sAh, sAl, tid);
            stage_op<false>(nullptr,nullptr,Bf32, LDK, tn*128, kk, sBh, sBl, tid);
        } else {
            stage_op<true >(AsH, AsL, nullptr, LDK, tm*128, kk, sAh, sAl, tid);
            stage_op<true >(BsH, BsL, nullptr, LDK, tn*128, kk, sBh, sBl, tid);
        }
        __syncthreads();

        bf16x8 ah[4], al[4], bh[4], bl[4];
#pragma unroll
        for (int m = 0; m < 4; ++m) {
            ah[m] = *(const bf16x8*)((const char*)sAh + aoff[m]);
            al[m] = *(const bf16x8*)((const char*)sAl + aoff[m]);
        }
#pragma unroll
        for (int n = 0; n < 4; ++n) {
            bh[n] = *(const bf16x8*)((const char*)sBh + boff[n]);
            bl[n] = *(const bf16x8*)((const char*)sBl + boff[n]);
        }
#pragma unroll
        for (int m = 0; m < 4; ++m)
#pragma unroll
            for (int n = 0; n < 4; ++n) {
                acc[m][n] = __builtin_amdgcn_mfma_f32_16x16x32_bf16(ah[m], bh[n], acc[m][n], 0, 0, 0);
                acc[m][n] = __builtin_amdgcn_mfma_f32_16x16x32_bf16(ah[m], bl[n], acc[m][n], 0, 0, 0);
                acc[m][n] = __builtin_amdgcn_mfma_f32_16x16x32_bf16(al[m], bh[n], acc[m][n], 0, 0, 0);
            }
    }

    // epilogue: C/D layout col=lane&15, row=(lane>>4)*4+i  [m89]
#pragma unroll
    for (int m = 0; m < 4; ++m)
#pragma unroll
        for (int n = 0; n < 4; ++n) {
            int colg = tn*128 + wc*64 + n*16 + frow;
#pragma unroll
            for (int i = 0; i < 4; ++i) {
                int rowg = tm*128 + wr*64 + m*16 + fk*4 + i;
                size_t idx = (size_t)rowg * LDO + colg;
                float v = acc[m][n][i];
                if constexpr (MODE == 1) {
                    v = v * scale - ((rowg == colg) ? dsub : 0.f);
                } else if constexpr (MODE == 2) {
                    float b2 = bf2f(outH[idx]) + bf2f(outH[idx + LO_OFF]);
                    v = alpha * v - b2 + ((rowg == colg) ? ck : 0.f);
                }
                u16 hb = f2bf(v);
                outH[idx] = hb;
                outL[idx] = f2bf(v - bf2f(hb));
            }
        }
}

// Clenshaw init: P = b_{n-1} = c_{n-1} I + 2 c_n Mt ; Q = b_n = c_n I  (split stores)
__global__ void k_init(const u16* MtH, u16* PH, u16* QH,
                       float c_n, float c_n1, int npairs)
{
    int idx = blockIdx.x * 256 + threadIdx.x;
    if (idx >= (npairs << 16)) return;
    int g = idx >> 16, e = idx & 65535;
    int rr = e >> 8, cc = e & 255;
    const u16* mt = MtH + (size_t)g * SLOT_U16;
    float m = bf2f(mt[e]) + bf2f(mt[e + LO_OFF]);
    float diag = (rr == cc) ? 1.f : 0.f;
    u16* pp = PH + (size_t)g * SLOT_U16;
    u16* qq = QH + (size_t)g * SLOT_U16;
    float b1 = 2.f * c_n * m + diag * c_n1;
    u16 hb = f2bf(b1);
    pp[e] = hb; pp[e + LO_OFF] = f2bf(b1 - bf2f(hb));
    float b0 = diag * c_n;
    hb = f2bf(b0);
    qq[e] = hb; qq[e + LO_OFF] = f2bf(b0 - bf2f(hb));
}

// finalize: fp32 result = hi + lo from Q region
__global__ void k_fin(const u16* QH, float* dst, int npairs) {
    int idx = blockIdx.x * 256 + threadIdx.x;
    if (idx >= (npairs << 16)) return;
    int g = idx >> 16, e = idx & 65535;
    const u16* q = QH + (size_t)g * SLOT_U16;
    dst[(size_t)g * SLOT_F32 + e] = bf2f(q[e]) + bf2f(q[e + LO_OFF]);
}

extern "C" void kernel_launch(void* const* d_in, const int* in_sizes, int n_in,
                              void* d_out, int out_size, void* d_ws, size_t ws_size,
                              hipStream_t stream)
{
    const float* X = (const float*)d_in[0];   // [64,512,512]
    const float* W = (const float*)d_in[1];   // [8,256,512]
    char* outc = (char*)d_out;                // 512 slots x 256KB

    // Chebyshev coeffs of log on [a,b]; spec(M) in [0.1, ~4.05]
    const double a = 0.094, b = 4.35;
    const double mid = 0.5*(a+b), hh = 0.5*(b-a);
    const double rr = mid/hh, z = rr - sqrt(rr*rr - 1.0);
    const double lnC = log(hh / (2.0*z));     // = c0/2
    const int NCH = 26;                       // truncation ~1e-4
    float c[NCH+1];
    {
        double zk = z;
        for (int k = 1; k <= NCH; ++k) { double v = 2.0*zk/(double)k; c[k] = (float)((k&1)? v : -v); zk *= z; }
        c[0] = (float)(2.0*lnC);
    }
    const float inv_h = (float)(1.0/hh), m_over_h = (float)(mid/hh);

    auto slotp = [&](int s){ return (u16*)(outc + (size_t)s * 262144); };

    int r = 0;  // batches done (64 total); group G batches, lazy BiMap + Clenshaw
    while (r < 64) {
        int G = (64 - r) / 3;
        bool special = (G < 1);
        if (special) G = 1;
        const int GP = G * 8, p0 = r * 8;

        u16 *PH, *QH, *MtH, *T1H, *T1L;
        if (!special) {
            PH  = slotp(p0);            // P (b_{k+1}) lives in dest slots
            MtH = slotp(p0 + GP);       // Mt region
            QH  = slotp(p0 + 2*GP);     // Q (b_{k+2})
            T1H = PH;  T1L = QH;        // T1 planes reuse P/Q regions (dead by init)
        } else {                        // last two single-batch groups
            MtH = slotp(p0);            // Mt in dest slots
            PH  = (u16*)d_ws;
            QH  = (u16*)((char*)d_ws + (2u << 20));
            T1H = (u16*)d_ws;           // T1 in ws (dead before init overwrites)
            T1L = (u16*)((char*)d_ws + (2u << 20));
        }

        // BiMap: T1 = W X (split-stored), then Mt = (T1 W^T - mid I)/h
        k_gemm<0><<<GP*8, 256, 0, stream>>>(W, X, nullptr, nullptr, nullptr,
                                            T1H, T1L, p0, 0.f, 0.f, 0.f, 0.f);
        k_gemm<1><<<GP*4, 256, 0, stream>>>(W, nullptr, T1H, T1L, nullptr,
                                            MtH, nullptr, p0, 0.f, 0.f, inv_h, m_over_h);
        // Clenshaw
        int blks = GP << 8;
        k_init<<<blks, 256, 0, stream>>>(MtH, PH, QH, c[NCH], c[NCH-1], GP);
        u16 *c1 = PH, *c2 = QH;
        for (int k = NCH - 2; k >= 1; --k) {   // 24 iterations (even -> result in Q)
            k_gemm<2><<<GP*4, 256, 0, stream>>>(nullptr, nullptr, MtH, nullptr, c1,
                                                c2, nullptr, 0, 2.f, c[k], 0.f, 0.f);
            u16* t = c1; c1 = c2; c2 = t;
        }
        // final: f = (c0/2) I + Mt b1 - b2  -> lands in QH
        k_gemm<2><<<GP*4, 256, 0, stream>>>(nullptr, nullptr, MtH, nullptr, c1,
                                            c2, nullptr, 0, 1.f, (float)lnC, 0.f, 0.f);
        k_fin<<<blks, 256, 0, stream>>>(QH, (float*)slotp(p0), GP);

        r += G;
    }
}

// Round 3
// 7928.334 us; speedup vs baseline: 1.2141x; 1.2141x over previous
//
#include <hip/hip_runtime.h>
#include <math.h>

// SPDNet: out = log(W X W^T) via Chebyshev matrix polynomial (ReEig no-op:
// spec(X) >= 0.1 exactly). All GEMMs bf16 MFMA, hi/lo split (3 passes).
// All outputs written TRANSPOSED (symmetric matrices; T1 via U = X W^T trick)
// so epilogues are 8B-vectorized. Pre-split operands stage via global_load_lds.

typedef unsigned short u16;
typedef __attribute__((ext_vector_type(8))) short bf16x8;
typedef __attribute__((ext_vector_type(4))) float f32x4;
typedef __attribute__((ext_vector_type(4))) unsigned short u16x4;

#define SLOT_U16 131072   // u16 elements per 256KB slot
#define LO_OFF   65536    // lo-plane offset within a state slot
#define AS1 __attribute__((address_space(1)))
#define AS3 __attribute__((address_space(3)))

__device__ __forceinline__ u16 f2bf(float x) {
    union { float f; unsigned u; } v; v.f = x;
    return (u16)((v.u + 0x7fffu + ((v.u >> 16) & 1u)) >> 16);
}
__device__ __forceinline__ float bf2f(u16 h) {
    union { float f; unsigned u; } v; v.u = ((unsigned)h) << 16; return v.f;
}

// paired-row swizzled LDS plane (8KB = 128 rows x 32 k of bf16), conflict-free
__device__ __forceinline__ int lds_byte(int row, int kch) {
    int line = row >> 1;
    int slot = (((row & 1) << 2) | kch) ^ (line & 7);
    return line * 128 + slot * 16;
}
__device__ __forceinline__ void lds_decode(int o, int& row, int& kch) {
    int line = o >> 7;
    int slot = ((o >> 4) & 7) ^ (line & 7);
    row = (line << 1) | (slot >> 2);
    kch = slot & 3;
}

__device__ __forceinline__ void gload16(const u16* g, u16* l) {
    __builtin_amdgcn_global_load_lds((AS1 void*)(g), (AS3 void*)(l), 16, 0, 0);
}

// MODE 0: U = X[b] * W[f]^T (512x256, K=512), written transposed => T1 (256x512) hi/lo planes
// MODE 1: Mt = (T1 * W[f]^T)*scale - dsub*I (256x256, K=512), written transposed (= itself)
// MODE 2: Bnew = alpha*Mt*B1 - B2 + ck*I, in-place over B2 slot (256x256, K=256)
template<int MODE>
__global__ __launch_bounds__(256) void k_gemm(
    const float* __restrict__ Wf, const float* __restrict__ Xf,
    const u16* __restrict__ AH, const u16* __restrict__ AL,
    const u16* __restrict__ BH,
    u16* OH, u16* OL,
    int p0, float alpha, float ck, float scale, float dsub)
{
    constexpr int KTOT = (MODE == 2) ? 256 : 512;
    constexpr int LDK  = (MODE == 2) ? 256 : 512;
    constexpr int LDO  = (MODE == 0) ? 512 : 256;

    __shared__ u16 sAh[4096], sAl[4096], sBh[4096], sBl[4096];

    const int tid = threadIdx.x, blk = blockIdx.x;
    int g, tm, tn;
    if constexpr (MODE == 0) { g = blk >> 3; tm = (blk >> 1) & 3; tn = blk & 1; }
    else                     { g = blk >> 2; tm = (blk >> 1) & 1; tn = blk & 1; }
    const int p = p0 + g, bidx = p >> 3, f = p & 7;

    // per-thread staging coords: two 16B chunks per plane
    const int o0 = tid * 16, o1 = o0 + 4096;
    int r0, k0, r1, k1;
    lds_decode(o0, r0, k0); lds_decode(o1, r1, k1);
    const int arb = tm * 128, brb = tn * 128;

    const float *Af32 = nullptr, *Bf32 = nullptr;
    const u16 *AsH = nullptr, *AsL = nullptr, *BsH = nullptr, *BsL = nullptr;
    if constexpr (MODE == 0) {
        Af32 = Xf + (size_t)bidx * 262144;     // X[b] 512x512 (symmetric)
        Bf32 = Wf + (size_t)f * 131072;        // W[f] 256x512
    } else if constexpr (MODE == 1) {
        AsH = AH + (size_t)g * SLOT_U16;       // T1 hi plane (256x512)
        AsL = AL + (size_t)g * SLOT_U16;       // T1 lo plane
        Bf32 = Wf + (size_t)f * 131072;
    } else {
        AsH = AH + (size_t)g * SLOT_U16; AsL = AsH + LO_OFF;   // Mt slot
        BsH = BH + (size_t)g * SLOT_U16; BsL = BsH + LO_OFF;   // B1 slot
    }

    auto stage_f32 = [&](const float* src, int rb, int kk, u16* ph, u16* pl) {
        const float* s0 = src + (size_t)(rb + r0) * LDK + kk + k0 * 8;
        const float* s1 = src + (size_t)(rb + r1) * LDK + kk + k1 * 8;
        float4 a0 = *(const float4*)s0, a1 = *(const float4*)(s0 + 4);
        float4 b0 = *(const float4*)s1, b1 = *(const float4*)(s1 + 4);
        float v0[8] = {a0.x,a0.y,a0.z,a0.w,a1.x,a1.y,a1.z,a1.w};
        float v1[8] = {b0.x,b0.y,b0.z,b0.w,b1.x,b1.y,b1.z,b1.w};
        bf16x8 h0, l0, h1, l1;
#pragma unroll
        for (int j = 0; j < 8; ++j) { u16 hb = f2bf(v0[j]); h0[j] = (short)hb; l0[j] = (short)f2bf(v0[j] - bf2f(hb)); }
#pragma unroll
        for (int j = 0; j < 8; ++j) { u16 hb = f2bf(v1[j]); h1[j] = (short)hb; l1[j] = (short)f2bf(v1[j] - bf2f(hb)); }
        *(bf16x8*)((char*)ph + o0) = h0; *(bf16x8*)((char*)pl + o0) = l0;
        *(bf16x8*)((char*)ph + o1) = h1; *(bf16x8*)((char*)pl + o1) = l1;
    };
    auto stage_gll = [&](const u16* sh, const u16* sl, int rb, int kk, u16* ph, u16* pl) {
        size_t e0 = (size_t)(rb + r0) * LDK + kk + k0 * 8;
        size_t e1 = (size_t)(rb + r1) * LDK + kk + k1 * 8;
        gload16(sh + e0, (u16*)((char*)ph + o0));
        gload16(sh + e1, (u16*)((char*)ph + o1));
        gload16(sl + e0, (u16*)((char*)pl + o0));
        gload16(sl + e1, (u16*)((char*)pl + o1));
    };

    const int lane = tid & 63, wid = tid >> 6;
    const int wr = wid >> 1, wc = wid & 1;
    const int frow = lane & 15, fk = lane >> 4;

    int aoff[4], boff[4];
#pragma unroll
    for (int m = 0; m < 4; ++m) aoff[m] = lds_byte(wr * 64 + m * 16 + frow, fk);
#pragma unroll
    for (int n = 0; n < 4; ++n) boff[n] = lds_byte(wc * 64 + n * 16 + frow, fk);

    f32x4 acc[4][4];
#pragma unroll
    for (int m = 0; m < 4; ++m)
#pragma unroll
        for (int n = 0; n < 4; ++n) acc[m][n] = (f32x4){0.f, 0.f, 0.f, 0.f};

    for (int kk = 0; kk < KTOT; kk += 32) {
        __syncthreads();
        if constexpr (MODE == 0) {
            stage_f32(Af32, arb, kk, sAh, sAl);
            stage_f32(Bf32, brb, kk, sBh, sBl);
        } else if constexpr (MODE == 1) {
            stage_gll(AsH, AsL, arb, kk, sAh, sAl);
            stage_f32(Bf32, brb, kk, sBh, sBl);
        } else {
            stage_gll(AsH, AsL, arb, kk, sAh, sAl);
            stage_gll(BsH, BsL, brb, kk, sBh, sBl);
        }
        __syncthreads();

        bf16x8 ah[4], al[4], bh[4], bl[4];
#pragma unroll
        for (int m = 0; m < 4; ++m) {
            ah[m] = *(const bf16x8*)((const char*)sAh + aoff[m]);
            al[m] = *(const bf16x8*)((const char*)sAl + aoff[m]);
        }
#pragma unroll
        for (int n = 0; n < 4; ++n) {
            bh[n] = *(const bf16x8*)((const char*)sBh + boff[n]);
            bl[n] = *(const bf16x8*)((const char*)sBl + boff[n]);
        }
#pragma unroll
        for (int m = 0; m < 4; ++m)
#pragma unroll
            for (int n = 0; n < 4; ++n) {
                acc[m][n] = __builtin_amdgcn_mfma_f32_16x16x32_bf16(ah[m], bh[n], acc[m][n], 0, 0, 0);
                acc[m][n] = __builtin_amdgcn_mfma_f32_16x16x32_bf16(ah[m], bl[n], acc[m][n], 0, 0, 0);
                acc[m][n] = __builtin_amdgcn_mfma_f32_16x16x32_bf16(al[m], bh[n], acc[m][n], 0, 0, 0);
            }
    }

    u16 *outH, *outL;
    if constexpr (MODE == 0) { outH = OH + (size_t)g * SLOT_U16; outL = OL + (size_t)g * SLOT_U16; }
    else                     { outH = OH + (size_t)g * SLOT_U16; outL = outH + LO_OFF; }

    // transposed write: value(rowg,colg) stored at [colg*LDO + rowg]; fragment's
    // 4 rows are consecutive => 8B-vector stores. C/D: col=lane&15, row=(lane>>4)*4+i.
#pragma unroll
    for (int m = 0; m < 4; ++m)
#pragma unroll
        for (int n = 0; n < 4; ++n) {
            const int colg = tn * 128 + wc * 64 + n * 16 + frow;
            const int rowg0 = tm * 128 + wr * 64 + m * 16 + fk * 4;
            size_t idx = (size_t)colg * LDO + rowg0;
            float v[4];
#pragma unroll
            for (int i = 0; i < 4; ++i) v[i] = acc[m][n][i];
            if constexpr (MODE == 1) {
#pragma unroll
                for (int i = 0; i < 4; ++i)
                    v[i] = v[i] * scale - ((rowg0 + i == colg) ? dsub : 0.f);
            } else if constexpr (MODE == 2) {
                u16x4 b2h = *(const u16x4*)(outH + idx);
                u16x4 b2l = *(const u16x4*)(outH + idx + LO_OFF);
#pragma unroll
                for (int i = 0; i < 4; ++i)
                    v[i] = alpha * v[i] - (bf2f(b2h[i]) + bf2f(b2l[i])) + ((rowg0 + i == colg) ? ck : 0.f);
            }
            u16x4 hv, lv;
#pragma unroll
            for (int i = 0; i < 4; ++i) { u16 hb = f2bf(v[i]); hv[i] = hb; lv[i] = f2bf(v[i] - bf2f(hb)); }
            *(u16x4*)(outH + idx) = hv;
            *(u16x4*)(outL + idx) = lv;
        }
}

// Clenshaw init: P = c_{n-1} I + 2 c_n Mt ; Q = c_n I   (4 elems/thread)
__global__ void k_init(const u16* __restrict__ MtH, u16* __restrict__ PH,
                       u16* __restrict__ QH, float c_n, float c_n1, int npairs)
{
    int e4 = (blockIdx.x * 256 + threadIdx.x) * 4;
    if (e4 >= (npairs << 16)) return;
    int g = e4 >> 16, e = e4 & 65535;
    int rr = e >> 8, cc = e & 255;
    const u16* mt = MtH + (size_t)g * SLOT_U16;
    u16x4 mh = *(const u16x4*)(mt + e), ml = *(const u16x4*)(mt + e + LO_OFF);
    u16x4 ph, pl, qh, ql;
#pragma unroll
    for (int j = 0; j < 4; ++j) {
        float m = bf2f(mh[j]) + bf2f(ml[j]);
        float d = (rr == cc + j) ? 1.f : 0.f;
        float b1 = 2.f * c_n * m + d * c_n1;
        u16 hb = f2bf(b1); ph[j] = hb; pl[j] = f2bf(b1 - bf2f(hb));
        float b0 = d * c_n;
        hb = f2bf(b0); qh[j] = hb; ql[j] = f2bf(b0 - bf2f(hb));
    }
    u16* pp = PH + (size_t)g * SLOT_U16;
    u16* qq = QH + (size_t)g * SLOT_U16;
    *(u16x4*)(pp + e) = ph; *(u16x4*)(pp + e + LO_OFF) = pl;
    *(u16x4*)(qq + e) = qh; *(u16x4*)(qq + e + LO_OFF) = ql;
}

__global__ void k_fin(const u16* __restrict__ QH, float* __restrict__ dst, int npairs)
{
    int e4 = (blockIdx.x * 256 + threadIdx.x) * 4;
    if (e4 >= (npairs << 16)) return;
    int g = e4 >> 16, e = e4 & 65535;
    const u16* q = QH + (size_t)g * SLOT_U16;
    u16x4 h = *(const u16x4*)(q + e), l = *(const u16x4*)(q + e + LO_OFF);
    float4 o;
    o.x = bf2f(h[0]) + bf2f(l[0]);
    o.y = bf2f(h[1]) + bf2f(l[1]);
    o.z = bf2f(h[2]) + bf2f(l[2]);
    o.w = bf2f(h[3]) + bf2f(l[3]);
    *(float4*)(dst + (size_t)g * 65536 + e) = o;
}

extern "C" void kernel_launch(void* const* d_in, const int* in_sizes, int n_in,
                              void* d_out, int out_size, void* d_ws, size_t ws_size,
                              hipStream_t stream)
{
    const float* X = (const float*)d_in[0];   // [64,512,512]
    const float* W = (const float*)d_in[1];   // [8,256,512]
    char* outc = (char*)d_out;                // 512 slots x 256KB

    // Chebyshev coeffs of log on [a,b]; spec(M) in [0.1, ~4.1]
    const double a = 0.094, b = 4.35;
    const double mid = 0.5 * (a + b), hh = 0.5 * (b - a);
    const double rrat = mid / hh, z = rrat - sqrt(rrat * rrat - 1.0);
    const double lnC = log(hh / (2.0 * z));   // c0/2
    const int NCH = 24;                       // truncation ~1.9e-4
    float c[NCH + 1];
    {
        double zk = z;
        for (int k = 1; k <= NCH; ++k) { double v = 2.0 * zk / (double)k; c[k] = (float)((k & 1) ? v : -v); zk *= z; }
        c[0] = (float)(2.0 * lnC);
    }
    const float inv_h = (float)(1.0 / hh), m_over_h = (float)(mid / hh);

    auto slot = [&](int s) { return (u16*)(outc + (size_t)s * 262144); };

    int done = 0;
    while (done < 64) {
        const int p0s = done * 8;
        const int freeSlots = 512 - p0s;
        int G = freeSlots / 24;
        if (G > 64 - done) G = 64 - done;
        u16 *P, *Mt, *Q;
        if (G >= 1) {
            int GPs = G * 8;
            P = slot(p0s); Mt = slot(p0s + GPs); Q = slot(p0s + 2 * GPs);
        } else {                              // tail: borrow ws (needs 4MB)
            G = 1;
            if (freeSlots >= 16) { P = slot(p0s); Mt = slot(p0s + 8); Q = (u16*)d_ws; }
            else { P = slot(p0s); Mt = (u16*)d_ws; Q = (u16*)d_ws + (size_t)8 * SLOT_U16; }
        }
        const int GP = G * 8;

        // BiMap: T1 planes (hi in P region, lo in Q region; dead before k_init)
        k_gemm<0><<<GP * 8, 256, 0, stream>>>(W, X, nullptr, nullptr, nullptr,
                                              P, Q, p0s, 0.f, 0.f, 0.f, 0.f);
        k_gemm<1><<<GP * 4, 256, 0, stream>>>(W, nullptr, P, Q, nullptr,
                                              Mt, nullptr, p0s, 0.f, 0.f, inv_h, m_over_h);
        k_init<<<GP * 64, 256, 0, stream>>>(Mt, P, Q, c[NCH], c[NCH - 1], GP);
        u16 *c1 = P, *c2 = Q;
        for (int k = NCH - 2; k >= 1; --k) {  // 22 steps (even -> final lands in Q buf)
            k_gemm<2><<<GP * 4, 256, 0, stream>>>(nullptr, nullptr, Mt, nullptr, c1,
                                                  c2, nullptr, 0, 2.f, c[k], 0.f, 0.f);
            u16* t = c1; c1 = c2; c2 = t;
        }
        k_gemm<2><<<GP * 4, 256, 0, stream>>>(nullptr, nullptr, Mt, nullptr, c1,
                                              c2, nullptr, 0, 1.f, (float)lnC, 0.f, 0.f);
        k_fin<<<GP * 64, 256, 0, stream>>>(c2, (float*)slot(p0s), GP);
        done += G;
    }
}

// Round 4
// 3526.463 us; speedup vs baseline: 2.7297x; 2.2482x over previous
//
#include <hip/hip_runtime.h>
#include <math.h>

// SPDNet: out = log(W X W^T) via Chebyshev matrix polynomial (ReEig no-op:
// spec(X) >= 0.1). bf16 MFMA, hi/lo split (3 passes). All outputs written
// transposed (everything symmetric; U = X W^T halves via the symmetry trick).
// Per-pair buffers: D (dest slot), M (Mt), S (ping-pong). Clenshaw ping-pongs
// D<->S; final GEMM lands hi/lo in D; k_fin converts D->S fp32; memcpy S->D.

typedef unsigned short u16;
typedef __attribute__((ext_vector_type(8))) short bf16x8;
typedef __attribute__((ext_vector_type(4))) float f32x4;
typedef __attribute__((ext_vector_type(4))) unsigned short u16x4;

#define SLOT_U16 131072   // u16 per 256KB slot
#define LO_OFF   65536    // lo-plane offset (u16 elements)
#define AS1 __attribute__((address_space(1)))
#define AS3 __attribute__((address_space(3)))

__device__ __forceinline__ u16 f2bf(float x) {
    union { float f; unsigned u; } v; v.f = x;
    return (u16)((v.u + 0x7fffu + ((v.u >> 16) & 1u)) >> 16);
}
__device__ __forceinline__ float bf2f(u16 h) {
    union { float f; unsigned u; } v; v.u = ((unsigned)h) << 16; return v.f;
}

// paired-row swizzled LDS plane (8KB = 128 rows x 32 k of bf16), 2-way max
__device__ __forceinline__ int lds_byte(int row, int kch) {
    int line = row >> 1;
    int slot = (((row & 1) << 2) | kch) ^ (line & 7);
    return line * 128 + slot * 16;
}
__device__ __forceinline__ void lds_decode(int o, int& row, int& kch) {
    int line = o >> 7;
    int slot = ((o >> 4) & 7) ^ (line & 7);
    row = (line << 1) | (slot >> 2);
    kch = slot & 3;
}
__device__ __forceinline__ void gload16(const u16* g, u16* l) {
    __builtin_amdgcn_global_load_lds((AS1 void*)(g), (AS3 void*)(l), 16, 0, 0);
}

// MODE 0: U-half^T = (X_half * W^T)^T -> D slot (hi/lo). A=f32 X(+aoff), B=f32 W. K=512.
// MODE 1: Macc = W[:,0:256] * U1 -> M slot (hi/lo split store). A=f32 W, B=u16 D. K=256.
// MODE 2: Mt = (Macc + W[:,256:]*U2)*scale - dsub*I -> M (in-place over Macc);
//         P-init = 2*cN*Mt + cN1*I -> S.  A=f32 W(+256), B=u16 D. K=256.
// MODE 3: step: v = alpha*(Mt*B) - b2 + ck*I -> target (in-place over b2).
//         b2 implicit cN*I when firstFlag. A=u16 M, B=u16 (S or D). K=256.
template<int MODE>
__global__ __launch_bounds__(256, 3) void k_gemm(
    const float* __restrict__ Af32, const u16* __restrict__ Au16,
    const float* __restrict__ Bf32, const u16* __restrict__ Bu16,
    u16* OU, u16* SU,
    int p0, int aoff,
    float alpha, float ck, float scale, float dsub,
    float cN, float cN1, int firstFlag)
{
    constexpr int KTOT = (MODE == 0) ? 512 : 256;

    __shared__ u16 sAh[4096], sAl[4096], sBh[4096], sBl[4096];

    const int tid = threadIdx.x, blk = blockIdx.x;
    // XCD swizzle: 4 blocks of pair g land on one XCD (g % 8 == blk % 8)
    const int xx = blk & 7, j = blk >> 3;
    const int t = j & 3, q = j >> 2;
    const int g = q * 8 + xx, tm = t >> 1, tn = t & 1;
    const int p = p0 + g, bidx = p >> 3, f = p & 7;

    const int o0 = tid * 16, o1 = o0 + 4096;
    int r0, k0, r1, k1;
    lds_decode(o0, r0, k0); lds_decode(o1, r1, k1);

    const float *Asrc = nullptr, *Bsrcf = nullptr;
    const u16 *AsH = nullptr, *AsL = nullptr, *BsH = nullptr, *BsL = nullptr;
    if constexpr (MODE == 0) {
        Asrc  = Af32 + (size_t)bidx * 262144 + aoff;   // X half (rows 256)
        Bsrcf = Bf32 + (size_t)f * 131072;             // W[f]
    } else if constexpr (MODE == 1 || MODE == 2) {
        Asrc = Af32 + (size_t)f * 131072 + aoff;       // W[f] col-slice
        BsH  = Bu16 + (size_t)g * SLOT_U16;            // U_half^T
        BsL  = BsH + LO_OFF;
    } else {
        AsH = Au16 + (size_t)g * SLOT_U16;             // Mt
        AsL = AsH + LO_OFF;
        BsH = Bu16 + (size_t)g * SLOT_U16;             // b_{k+1}
        BsL = BsH + LO_OFF;
    }
    const int ldA = (MODE == 3) ? 256 : 512;
    const int ldB = (MODE == 0) ? 512 : 256;
    const int arb = tm * 128, brb = tn * 128;

    auto stage_f32 = [&](const float* src, int rb, int ld, int kk, u16* ph, u16* pl) {
        const float* s0 = src + (size_t)(rb + r0) * ld + kk + k0 * 8;
        const float* s1 = src + (size_t)(rb + r1) * ld + kk + k1 * 8;
        float4 a0 = *(const float4*)s0, a1 = *(const float4*)(s0 + 4);
        float4 b0 = *(const float4*)s1, b1 = *(const float4*)(s1 + 4);
        float v0[8] = {a0.x,a0.y,a0.z,a0.w,a1.x,a1.y,a1.z,a1.w};
        float v1[8] = {b0.x,b0.y,b0.z,b0.w,b1.x,b1.y,b1.z,b1.w};
        bf16x8 h0, l0, h1, l1;
#pragma unroll
        for (int i = 0; i < 8; ++i) { u16 hb = f2bf(v0[i]); h0[i] = (short)hb; l0[i] = (short)f2bf(v0[i] - bf2f(hb)); }
#pragma unroll
        for (int i = 0; i < 8; ++i) { u16 hb = f2bf(v1[i]); h1[i] = (short)hb; l1[i] = (short)f2bf(v1[i] - bf2f(hb)); }
        *(bf16x8*)((char*)ph + o0) = h0; *(bf16x8*)((char*)pl + o0) = l0;
        *(bf16x8*)((char*)ph + o1) = h1; *(bf16x8*)((char*)pl + o1) = l1;
    };
    auto stage_gll = [&](const u16* sh, const u16* sl, int rb, int ld, int kk, u16* ph, u16* pl) {
        size_t e0 = (size_t)(rb + r0) * ld + kk + k0 * 8;
        size_t e1 = (size_t)(rb + r1) * ld + kk + k1 * 8;
        gload16(sh + e0, (u16*)((char*)ph + o0));
        gload16(sh + e1, (u16*)((char*)ph + o1));
        gload16(sl + e0, (u16*)((char*)pl + o0));
        gload16(sl + e1, (u16*)((char*)pl + o1));
    };

    const int lane = tid & 63, wid = tid >> 6;
    const int wr = wid >> 1, wc = wid & 1;
    const int frow = lane & 15, fk = lane >> 4;

    int aoffl[4], boffl[4];
#pragma unroll
    for (int m = 0; m < 4; ++m) aoffl[m] = lds_byte(wr * 64 + m * 16 + frow, fk);
#pragma unroll
    for (int n = 0; n < 4; ++n) boffl[n] = lds_byte(wc * 64 + n * 16 + frow, fk);

    f32x4 acc[4][4];
#pragma unroll
    for (int m = 0; m < 4; ++m)
#pragma unroll
        for (int n = 0; n < 4; ++n) acc[m][n] = (f32x4){0.f, 0.f, 0.f, 0.f};

    for (int kk = 0; kk < KTOT; kk += 32) {
        __syncthreads();
        if constexpr (MODE == 0) {
            stage_f32(Asrc, arb, ldA, kk, sAh, sAl);
            stage_f32(Bsrcf, brb, ldB, kk, sBh, sBl);
        } else if constexpr (MODE == 1 || MODE == 2) {
            stage_f32(Asrc, arb, ldA, kk, sAh, sAl);
            stage_gll(BsH, BsL, brb, ldB, kk, sBh, sBl);
        } else {
            stage_gll(AsH, AsL, arb, ldA, kk, sAh, sAl);
            stage_gll(BsH, BsL, brb, ldB, kk, sBh, sBl);
        }
        __syncthreads();

        bf16x8 ah[4], al[4], bh[4], bl[4];
#pragma unroll
        for (int m = 0; m < 4; ++m) {
            ah[m] = *(const bf16x8*)((const char*)sAh + aoffl[m]);
            al[m] = *(const bf16x8*)((const char*)sAl + aoffl[m]);
        }
#pragma unroll
        for (int n = 0; n < 4; ++n) {
            bh[n] = *(const bf16x8*)((const char*)sBh + boffl[n]);
            bl[n] = *(const bf16x8*)((const char*)sBl + boffl[n]);
        }
#pragma unroll
        for (int m = 0; m < 4; ++m)
#pragma unroll
            for (int n = 0; n < 4; ++n) {
                acc[m][n] = __builtin_amdgcn_mfma_f32_16x16x32_bf16(ah[m], bh[n], acc[m][n], 0, 0, 0);
                acc[m][n] = __builtin_amdgcn_mfma_f32_16x16x32_bf16(ah[m], bl[n], acc[m][n], 0, 0, 0);
                acc[m][n] = __builtin_amdgcn_mfma_f32_16x16x32_bf16(al[m], bh[n], acc[m][n], 0, 0, 0);
            }
    }

    u16* outH = OU + (size_t)g * SLOT_U16;
    u16* pH   = (MODE == 2) ? SU + (size_t)g * SLOT_U16 : nullptr;

    // transposed store: value(rowg,colg) at [colg*256+rowg]; all outputs
    // symmetric (or consumed as B^T), fragment rows contiguous -> 8B vectors.
#pragma unroll
    for (int m = 0; m < 4; ++m)
#pragma unroll
        for (int n = 0; n < 4; ++n) {
            const int colg = tn * 128 + wc * 64 + n * 16 + frow;
            const int rowg0 = tm * 128 + wr * 64 + m * 16 + fk * 4;
            size_t idx = (size_t)colg * 256 + rowg0;
            float v[4];
#pragma unroll
            for (int i = 0; i < 4; ++i) v[i] = acc[m][n][i];
            if constexpr (MODE == 2) {
                u16x4 mh = *(const u16x4*)(outH + idx);
                u16x4 ml = *(const u16x4*)(outH + idx + LO_OFF);
                u16x4 hv, lv, ph2, pl2;
#pragma unroll
                for (int i = 0; i < 4; ++i) {
                    float mt = (v[i] + bf2f(mh[i]) + bf2f(ml[i])) * scale
                             - ((rowg0 + i == colg) ? dsub : 0.f);
                    u16 hb = f2bf(mt); hv[i] = hb; lv[i] = f2bf(mt - bf2f(hb));
                    float pv = 2.f * cN * mt + ((rowg0 + i == colg) ? cN1 : 0.f);
                    hb = f2bf(pv); ph2[i] = hb; pl2[i] = f2bf(pv - bf2f(hb));
                }
                *(u16x4*)(outH + idx) = hv;
                *(u16x4*)(outH + idx + LO_OFF) = lv;
                *(u16x4*)(pH + idx) = ph2;
                *(u16x4*)(pH + idx + LO_OFF) = pl2;
            } else {
                if constexpr (MODE == 3) {
                    if (firstFlag) {
#pragma unroll
                        for (int i = 0; i < 4; ++i)
                            v[i] = alpha * v[i] - ((rowg0 + i == colg) ? cN : 0.f)
                                 + ((rowg0 + i == colg) ? ck : 0.f);
                    } else {
                        u16x4 b2h = *(const u16x4*)(outH + idx);
                        u16x4 b2l = *(const u16x4*)(outH + idx + LO_OFF);
#pragma unroll
                        for (int i = 0; i < 4; ++i)
                            v[i] = alpha * v[i] - (bf2f(b2h[i]) + bf2f(b2l[i]))
                                 + ((rowg0 + i == colg) ? ck : 0.f);
                    }
                }
                u16x4 hv, lv;
#pragma unroll
                for (int i = 0; i < 4; ++i) { u16 hb = f2bf(v[i]); hv[i] = hb; lv[i] = f2bf(v[i] - bf2f(hb)); }
                *(u16x4*)(outH + idx) = hv;
                *(u16x4*)(outH + idx + LO_OFF) = lv;
            }
        }
}

// D (hi/lo) -> S (fp32); host then memcpys S -> D.
__global__ void k_fin(const u16* __restrict__ DH, float* __restrict__ dst, int npairs)
{
    int e4 = (blockIdx.x * 256 + threadIdx.x) * 4;
    if (e4 >= (npairs << 16)) return;
    int g = e4 >> 16, e = e4 & 65535;
    const u16* qp = DH + (size_t)g * SLOT_U16;
    u16x4 h = *(const u16x4*)(qp + e), l = *(const u16x4*)(qp + e + LO_OFF);
    float4 o;
    o.x = bf2f(h[0]) + bf2f(l[0]);
    o.y = bf2f(h[1]) + bf2f(l[1]);
    o.z = bf2f(h[2]) + bf2f(l[2]);
    o.w = bf2f(h[3]) + bf2f(l[3]);
    *(float4*)(dst + (size_t)g * 65536 + e) = o;
}

extern "C" void kernel_launch(void* const* d_in, const int* in_sizes, int n_in,
                              void* d_out, int out_size, void* d_ws, size_t ws_size,
                              hipStream_t stream)
{
    const float* X = (const float*)d_in[0];   // [64,512,512]
    const float* W = (const float*)d_in[1];   // [8,256,512]
    char* outc = (char*)d_out;                // 512 slots x 256KB

    // Chebyshev log on [a,b]; spec(M) in [0.1, ~4.1]
    const double a = 0.094, b = 4.30;
    const double mid = 0.5 * (a + b), hh = 0.5 * (b - a);
    const double rrat = mid / hh, z = rrat - sqrt(rrat * rrat - 1.0);
    const double lnC = log(hh / (2.0 * z));   // c0/2
    const int NCH = 18;                        // truncation ~1.4e-3
    float c[NCH + 1];
    {
        double zk = z;
        for (int k = 1; k <= NCH; ++k) { double v = 2.0 * zk / (double)k; c[k] = (float)((k & 1) ? v : -v); zk *= z; }
        c[0] = (float)(2.0 * lnC);
    }
    const float inv_h = (float)(1.0 / hh), m_over_h = (float)(mid / hh);
    const float cNf = c[NCH], cN1f = c[NCH - 1];

    auto slot = [&](int s) { return (u16*)(outc + (size_t)s * 262144); };
    const int wsSlots = (int)(ws_size / 262144);

    int done = 0;
    while (done < 64) {
        const int p0s = done * 8;
        int G = 64 - done; if (G > 21) G = 21;
        int placement = -1;
        for (; G >= 1; --G) {
            int freerun = 512 - 8 * done - 8 * G;
            if (16 * G <= freerun)                      { placement = 0; break; }
            if (8 * G <= freerun && 8 * G <= wsSlots)   { placement = 1; break; }
            if (16 * G <= wsSlots)                      { placement = 2; break; }
        }
        const int GP = G * 8;
        u16* DH = slot(p0s);
        u16 *MH, *SH;
        if (placement == 0)      { MH = slot(p0s + 8 * G); SH = slot(p0s + 16 * G); }
        else if (placement == 1) { MH = slot(p0s + 8 * G); SH = (u16*)d_ws; }
        else                     { MH = (u16*)d_ws;        SH = (u16*)d_ws + (size_t)GP * SLOT_U16; }

        const int nb = GP * 4;
        // BiMap (K-split through D): U1^T -> D; Macc -> M; U2^T -> D; Mt -> M, P -> S
        k_gemm<0><<<nb, 256, 0, stream>>>(X, nullptr, W, nullptr, DH, nullptr,
                                          p0s, 0, 0.f, 0.f, 0.f, 0.f, 0.f, 0.f, 0);
        k_gemm<1><<<nb, 256, 0, stream>>>(W, nullptr, nullptr, DH, MH, nullptr,
                                          p0s, 0, 0.f, 0.f, 0.f, 0.f, 0.f, 0.f, 0);
        k_gemm<0><<<nb, 256, 0, stream>>>(X, nullptr, W, nullptr, DH, nullptr,
                                          p0s, 131072, 0.f, 0.f, 0.f, 0.f, 0.f, 0.f, 0);
        k_gemm<2><<<nb, 256, 0, stream>>>(W, nullptr, nullptr, DH, MH, SH,
                                          p0s, 256, 0.f, 0.f, inv_h, m_over_h, cNf, cN1f, 0);
        // Clenshaw: s=1..NCH-2, target alternates D,S,...; first step b2 = cN*I
        for (int s = 1; s <= NCH - 2; ++s) {
            const u16* Bsrc = (s & 1) ? SH : DH;
            u16* Tgt       = (s & 1) ? DH : SH;
            k_gemm<3><<<nb, 256, 0, stream>>>(nullptr, MH, nullptr, Bsrc, Tgt, nullptr,
                                              p0s, 0, 2.f, c[NCH - 1 - s], 0.f, 0.f,
                                              cNf, 0.f, (s == 1) ? 1 : 0);
        }
        // final: out = lnC*I + Mt*b1 - b2 ; b1 in S, b2 in D -> hi/lo into D
        k_gemm<3><<<nb, 256, 0, stream>>>(nullptr, MH, nullptr, SH, DH, nullptr,
                                          p0s, 0, 1.f, (float)lnC, 0.f, 0.f, cNf, 0.f, 0);
        // convert D(hi/lo) -> S(fp32), then copy into dest slots
        k_fin<<<GP * 64, 256, 0, stream>>>(DH, (float*)SH, GP);
        hipMemcpyAsync(DH, SH, (size_t)GP * 262144, hipMemcpyDeviceToDevice, stream);

        done += G;
    }
}